// Round 5
// baseline (113.037 us; speedup 1.0000x reference)
//
#include <hip/hip_runtime.h>

// Problem constants (from reference)
#define SPP   16
#define SH    256
#define SW    256
#define HI    1024
#define WI    1024
#define CH    3
#define BATCH 4

// tanh via v_exp_f32; |arg| <= ~1.2 here, abs error ~1e-6 (threshold 1.7e-2).
__device__ __forceinline__ float fast_tanh(float x) {
    const float e = __expf(2.0f * x);
    return (e - 1.0f) * __builtin_amdgcn_rcpf(e + 1.0f);
}

// One thread = one (sensor px, spp) sample point. Geometry (tanh warp,
// bilinear weights, det) computed ONCE, then reused across all 4 batches
// (the warp is batch-independent). Wave = 4 consecutive sensor px x 16 spp:
// the wave's gather footprint is ~33 img px wide x ~12 img rows tall, so a
// 64-lane gather instruction touches only ~24 unique cache lines (vs ~50
// with a 32-px-wide mapping) -> lower TA-pipe cost per gather.
//
// spp lives in lane bits 0..3, so the 16-spp reduction is a 4-step
// __shfl_xor butterfly within each 16-lane group.
//
// Border algebra: xb = min(floor(gx), W-2), fx = gx - xb (fx reaches 1.0 at
// the border) — identical to the reference's clamp.
__global__ __launch_bounds__(256) void foveated_batch(
    const float* __restrict__ img,
    const float* __restrict__ t_ptr,
    const float* __restrict__ jitter,
    float* __restrict__ out)
{
    // 4096 logical blocks: L>>4 = sensor row, L&15 = 16-px group.
    // XCD slab swizzle: each XCD gets 512 contiguous logical blocks
    // (= 32 sensor rows -> ~1.2 MB img slab, L2-resident).
    const int L   = (blockIdx.x & 7) * 512 + (blockIdx.x >> 3);
    const int sy  = L >> 4;
    const int sx0 = (L & 15) * 16;

    const int th  = threadIdx.x;
    const int sp  = th & 15;          // spp index (lane bits 0..3)
    const int pxl = th >> 4;          // px within 16-px group
    const int sx  = sx0 + pxl;

    const float step  = 2.0f / 256.0f;
    const float tt    = t_ptr[0];
    const float inv_s = __builtin_amdgcn_rcpf(fast_tanh(tt));

    // ---- geometry: once per (px, spp), shared by all 4 batches ----
    const float2 j = ((const float2*)jitter)[sp * (SH * SW) + sy * SW + sx];
    const float posx = (-1.0f + sx * step) + j.x * step;
    const float posy = (-1.0f + sy * step) + j.y * step;

    const float thx = fast_tanh(tt * posx);
    const float thy = fast_tanh(tt * posy);
    const float ddx = tt * (1.0f - thx * thx) * inv_s;
    const float ddy = tt * (1.0f - thy * thy) * inv_s;
    const float det = ddx * ddy;

    float gx = (thx * inv_s + 1.0f) * (WI * 0.5f) - 0.5f;
    float gy = (thy * inv_s + 1.0f) * (HI * 0.5f) - 0.5f;
    gx = fminf(fmaxf(gx, 0.0f), (float)(WI - 1));
    gy = fminf(fmaxf(gy, 0.0f), (float)(HI - 1));

    const int xb = min((int)gx, WI - 2);
    const int yb = min((int)gy, HI - 2);
    const float fx = gx - (float)xb;
    const float fy = gy - (float)yb;

    const float w00 = (1.0f - fx) * (1.0f - fy) * det;
    const float w01 = fx * (1.0f - fy) * det;
    const float w10 = (1.0f - fx) * fy * det;
    const float w11 = fx * fy * det;

    const int i0 = yb * WI + xb;      // row yb, cols xb..xb+1
    const int i1 = i0 + WI;           // row yb+1
    const size_t plane = (size_t)HI * WI;

    // ---- gather: 4 batches x 3 channels x 2 row-pair loads ----
    float acc[BATCH][CH];
    #pragma unroll
    for (int b = 0; b < BATCH; ++b) {
        const float* __restrict__ pb = img + (size_t)(b * CH) * plane;
        #pragma unroll
        for (int c = 0; c < CH; ++c) {
            const float* __restrict__ p = pb + c * plane;
            const float2 a = *(const float2*)(p + i0);
            const float2 d = *(const float2*)(p + i1);
            acc[b][c] = a.x * w00 + a.y * w01 + d.x * w10 + d.y * w11;
        }
    }

    // ---- reduce the 16 spp (butterfly within each 16-lane group) ----
    float dsum = det;
    #pragma unroll
    for (int m = 1; m < 16; m <<= 1) {
        #pragma unroll
        for (int b = 0; b < BATCH; ++b)
            #pragma unroll
            for (int c = 0; c < CH; ++c)
                acc[b][c] += __shfl_xor(acc[b][c], m);
        dsum += __shfl_xor(dsum, m);
    }

    if (sp == 0) {
        const float inv_d = 1.0f / dsum;
        const int pix = sy * SW + sx;
        #pragma unroll
        for (int b = 0; b < BATCH; ++b)
            #pragma unroll
            for (int c = 0; c < CH; ++c)
                out[(size_t)(b * CH + c) * (SH * SW) + pix] = acc[b][c] * inv_d;
    }
}

extern "C" void kernel_launch(void* const* d_in, const int* in_sizes, int n_in,
                              void* d_out, int out_size, void* d_ws, size_t ws_size,
                              hipStream_t stream) {
    const float* img    = (const float*)d_in[0];
    const float* t      = (const float*)d_in[1];
    const float* jitter = (const float*)d_in[2];
    float* out          = (float*)d_out;

    // 256 rows x 16 px-groups = 4096 blocks; 256 threads = 16 px x 16 spp.
    hipLaunchKernelGGL(foveated_batch, dim3(4096), dim3(256), 0, stream,
                       img, t, jitter, out);
}